// Round 3
// baseline (144224.170 us; speedup 1.0000x reference)
//
#include <hip/hip_runtime.h>
#include <hip/hip_fp16.h>

#define B_SZ    64
#define T_STEPS 512
#define U1      128
#define S1      128
#define U2      256
#define S2      128
#define NUNF    6

__device__ __forceinline__ float fast_exp2(float x) { return __builtin_amdgcn_exp2f(x); }
__device__ __forceinline__ float fast_rcp(float x)  { return __builtin_amdgcn_rcpf(x); }

// ---------------------------------------------------------------------------
// Param transform, fp16-packed: AB = half2(sigma*log2e, mu*sigma*log2e),
// W = half(w*erev).  sigmoid((v-mu)*sigma) = 1/(1+exp2(B - A*v)); |W| = w*mask.
// 6 bytes per (s,uo) pair streamed in the hot loop.
// ---------------------------------------------------------------------------
__global__ void prep_half(const float* __restrict__ sg, const float* __restrict__ mu,
                          const float* __restrict__ w, const float* __restrict__ er,
                          __half2* __restrict__ AB, __half* __restrict__ W, int n)
{
    int i = blockIdx.x * 256 + threadIdx.x;
    if (i >= n) return;
    const float L2E = 1.4426950408889634f;
    float a = sg[i] * L2E;
    AB[i] = __floats2half2_rn(a, mu[i] * a);
    W[i]  = __float2half_rn(w[i] * er[i]);
}

__global__ void prep_vec(const float* __restrict__ gleak, const float* __restrict__ vleak,
                         const float* __restrict__ cm,
                         float* __restrict__ cmt, float* __restrict__ nb,
                         float* __restrict__ db, int n)
{
    int i = blockIdx.x * 256 + threadIdx.x;
    if (i >= n) return;
    float c6 = cm[i] * 6.f;
    float gl = gleak[i];
    cmt[i] = c6;
    nb[i]  = gl * vleak[i];
    db[i]  = c6 + gl + 1e-8f;
}

__device__ __forceinline__ void pair_eval(__half2 ab, __half w, float vj,
                                          float& an, float& ad)
{
    float a  = __low2float(ab);
    float bb = __high2float(ab);
    float ww = __half2float(w);
    float e  = fast_exp2(bb - a * vj);
    float r  = fast_rcp(1.f + e);
    an = fmaf(ww, r, an);
    ad = fmaf(fabsf(ww), r, ad);
}

// ---------------------------------------------------------------------------
// Fused pipeline kernel: 128 blocks.
//   blocks 0..63   : layer-1 LTC for batch b, publishing h1 rows + flags
//   blocks 64..127 : layer-2 LTC for batch b, spin-acquiring flags per step
// Producer is ~4x faster per step than consumer, so the consumer never waits
// after t=0.  Flags are zeroed each call via hipMemsetAsync.
// ---------------------------------------------------------------------------
__global__ __launch_bounds__(512, 1) void ltc_pipe(
    const float* __restrict__ x,
    const float* __restrict__ iw1, const float* __restrict__ ib1,
    const __half2* __restrict__ AB1s, const __half* __restrict__ W1s,
    const __half2* __restrict__ AB1r, const __half* __restrict__ W1r,
    const float* __restrict__ cmt1, const float* __restrict__ nb1, const float* __restrict__ db1,
    const float* __restrict__ ow1, const float* __restrict__ ob1,
    const float* __restrict__ iw2, const float* __restrict__ ib2,
    const __half2* __restrict__ AB2s, const __half* __restrict__ W2s,
    const __half2* __restrict__ AB2r, const __half* __restrict__ W2r,
    const float* __restrict__ cmt2, const float* __restrict__ nb2, const float* __restrict__ db2,
    const float* __restrict__ ow2, const float* __restrict__ ob2,
    float* __restrict__ h1, float* __restrict__ h2,
    unsigned int* __restrict__ flags)
{
    const int tid = threadIdx.x;

    if (blockIdx.x < 64) {
        // ------------------------- producer: layer 1 -------------------------
        const int b  = blockIdx.x;
        const int uo = tid & (U1 - 1);
        const int g  = tid >> 7;               // 4 groups x 32 inputs

        __shared__ float  v1[U1];
        __shared__ float  ibuf1[S1];
        __shared__ float2 red1[4][U1];
        __shared__ float  nbs1[U1], dbs1[U1];

        float c_cmt = 0, c_nb = 0, c_db = 0, c_iw = 0, c_ib = 0, c_ow = 0, c_ob = 0;
        if (tid < U1) {
            v1[tid] = 0.f;
            c_cmt = cmt1[tid]; c_nb = nb1[tid]; c_db = db1[tid];
            c_iw = iw1[tid];   c_ib = ib1[tid];
            c_ow = ow1[tid];   c_ob = ob1[tid];
        }
        const float* xb = x  + (size_t)b * T_STEPS * S1;
        float*       hb = h1 + (size_t)b * T_STEPS * U1;

        const __half2* pABs = AB1s + (size_t)(g * 32) * U1 + uo;
        const __half*  pWs  = W1s  + (size_t)(g * 32) * U1 + uo;
        const __half2* pABr = AB1r + (size_t)(g * 32) * U1 + uo;
        const __half*  pWr  = W1r  + (size_t)(g * 32) * U1 + uo;

        for (int t = 0; t < T_STEPS; ++t) {
            if (tid < S1) ibuf1[tid] = fmaf(xb[t * S1 + tid], c_iw, c_ib);
            __syncthreads();

            {   // sensory partials
                float an = 0.f, ad = 0.f;
                #pragma unroll
                for (int jj = 0; jj < 8; ++jj) {
                    float4 iv = *reinterpret_cast<const float4*>(&ibuf1[g * 32 + jj * 4]);
                    float vals[4] = {iv.x, iv.y, iv.z, iv.w};
                    #pragma unroll
                    for (int q = 0; q < 4; ++q) {
                        int j = jj * 4 + q;
                        pair_eval(pABs[(size_t)j * U1], pWs[(size_t)j * U1], vals[q], an, ad);
                    }
                }
                red1[g][uo] = make_float2(an, ad);
            }
            __syncthreads();
            if (tid < U1) {
                float2 r0 = red1[0][tid], r1 = red1[1][tid], r2 = red1[2][tid], r3 = red1[3][tid];
                nbs1[tid] = c_nb + ((r0.x + r1.x) + (r2.x + r3.x));
                dbs1[tid] = c_db + ((r0.y + r1.y) + (r2.y + r3.y));
            }
            __syncthreads();

            for (int k = 0; k < NUNF; ++k) {
                float an = 0.f, ad = 0.f;
                #pragma unroll
                for (int jj = 0; jj < 8; ++jj) {
                    float4 vv = *reinterpret_cast<const float4*>(&v1[g * 32 + jj * 4]);
                    float vals[4] = {vv.x, vv.y, vv.z, vv.w};
                    #pragma unroll
                    for (int q = 0; q < 4; ++q) {
                        int j = jj * 4 + q;
                        pair_eval(pABr[(size_t)j * U1], pWr[(size_t)j * U1], vals[q], an, ad);
                    }
                }
                red1[g][uo] = make_float2(an, ad);
                __syncthreads();
                if (tid < U1) {
                    float2 r0 = red1[0][tid], r1 = red1[1][tid], r2 = red1[2][tid], r3 = red1[3][tid];
                    float wn = nbs1[tid] + ((r0.x + r1.x) + (r2.x + r3.x));
                    float wd = dbs1[tid] + ((r0.y + r1.y) + (r2.y + r3.y));
                    v1[tid] = fmaf(c_cmt, v1[tid], wn) * fast_rcp(wd);
                }
                __syncthreads();
            }
            if (tid < U1) hb[t * U1 + tid] = fmaf(v1[tid], c_ow, c_ob);
            __syncthreads();   // drain both waves' h1 stores before publishing
            if (tid == 0)
                __hip_atomic_store(&flags[((size_t)b << 9) + t], 1u,
                                   __ATOMIC_RELEASE, __HIP_MEMORY_SCOPE_AGENT);
        }
    } else {
        // ------------------------- consumer: layer 2 -------------------------
        const int b  = blockIdx.x - 64;
        const int uo = tid & (U2 - 1);
        const int g  = tid >> 8;               // 2 groups x 128 inputs

        __shared__ float  v2[U2];
        __shared__ float  ibuf2[S2];
        __shared__ float2 red2[2][U2];
        __shared__ float  nbs2[U2], dbs2[U2];

        float c_cmt = 0, c_nb = 0, c_db = 0;
        if (tid < U2) {
            v2[tid] = 0.f;
            c_cmt = cmt2[tid]; c_nb = nb2[tid]; c_db = db2[tid];
        }
        float c_iw = 0, c_ib = 0;
        if (tid < S2) { c_iw = iw2[tid]; c_ib = ib2[tid]; }
        float c_ow = 0, c_ob = 0;
        if (tid < 64) { c_ow = ow2[tid]; c_ob = ob2[tid]; }

        const float* hb = h1 + (size_t)b * T_STEPS * S2;
        float*       op = h2 + (size_t)b * T_STEPS * 64;

        const __half2* pABs = AB2s + (size_t)(g * 64) * U2 + uo;
        const __half*  pWs  = W2s  + (size_t)(g * 64) * U2 + uo;
        const __half2* pABr = AB2r + (size_t)(g * 128) * U2 + uo;
        const __half*  pWr  = W2r  + (size_t)(g * 128) * U2 + uo;

        for (int t = 0; t < T_STEPS; ++t) {
            if (tid == 0) {
                while (__hip_atomic_load(&flags[((size_t)b << 9) + t],
                                         __ATOMIC_ACQUIRE, __HIP_MEMORY_SCOPE_AGENT) == 0u)
                    __builtin_amdgcn_s_sleep(2);
            }
            __syncthreads();
            if (tid < S2) ibuf2[tid] = fmaf(hb[t * S2 + tid], c_iw, c_ib);
            __syncthreads();

            {   // sensory partials: 64 pairs/thread
                float an = 0.f, ad = 0.f;
                #pragma unroll
                for (int jj = 0; jj < 16; ++jj) {
                    float4 iv = *reinterpret_cast<const float4*>(&ibuf2[g * 64 + jj * 4]);
                    float vals[4] = {iv.x, iv.y, iv.z, iv.w};
                    #pragma unroll
                    for (int q = 0; q < 4; ++q) {
                        int j = jj * 4 + q;
                        pair_eval(pABs[(size_t)j * U2], pWs[(size_t)j * U2], vals[q], an, ad);
                    }
                }
                red2[g][uo] = make_float2(an, ad);
            }
            __syncthreads();
            if (tid < U2) {
                float2 r0 = red2[0][tid], r1 = red2[1][tid];
                nbs2[tid] = c_nb + r0.x + r1.x;
                dbs2[tid] = c_db + r0.y + r1.y;
            }
            __syncthreads();

            for (int k = 0; k < NUNF; ++k) {
                float an = 0.f, ad = 0.f;   // recurrent: 128 pairs/thread
                #pragma unroll
                for (int jj = 0; jj < 32; ++jj) {
                    float4 vv = *reinterpret_cast<const float4*>(&v2[g * 128 + jj * 4]);
                    float vals[4] = {vv.x, vv.y, vv.z, vv.w};
                    #pragma unroll
                    for (int q = 0; q < 4; ++q) {
                        int j = jj * 4 + q;
                        pair_eval(pABr[(size_t)j * U2], pWr[(size_t)j * U2], vals[q], an, ad);
                    }
                }
                red2[g][uo] = make_float2(an, ad);
                __syncthreads();
                if (tid < U2) {
                    float2 r0 = red2[0][tid], r1 = red2[1][tid];
                    float wn = nbs2[tid] + r0.x + r1.x;
                    float wd = dbs2[tid] + r0.y + r1.y;
                    v2[tid] = fmaf(c_cmt, v2[tid], wn) * fast_rcp(wd);
                }
                __syncthreads();
            }
            if (tid < 64) op[t * 64 + tid] = fmaf(v2[tid], c_ow, c_ob);
        }
    }
}

// ---------------------------------------------------------------------------
// FC head: out[b,t,o] = fcb[o] + sum_k h2[b,t,k] * fcw[o,k]
// ---------------------------------------------------------------------------
__global__ __launch_bounds__(512, 1) void fc_head(
    const float* __restrict__ h2, const float* __restrict__ fcw,
    const float* __restrict__ fcb, float* __restrict__ out)
{
    __shared__ float fwT[64 * 64];
    __shared__ float hs[8 * 64];
    const int tid = threadIdx.x;
    for (int i = tid; i < 64 * 64; i += 512) {
        int o = i >> 6, k = i & 63;
        fwT[k * 64 + o] = fcw[i];
    }
    size_t base = (size_t)blockIdx.x * 8 * 64;
    hs[tid] = h2[base + tid];
    __syncthreads();
    const int o = tid & 63, tt = tid >> 6;
    float acc = fcb[o];
    #pragma unroll
    for (int k = 0; k < 64; ++k)
        acc = fmaf(hs[tt * 64 + k], fwT[k * 64 + o], acc);
    out[base + tt * 64 + o] = acc;
}

// ---------------------------------------------------------------------------
extern "C" void kernel_launch(void* const* d_in, const int* in_sizes, int n_in,
                              void* d_out, int out_size, void* d_ws, size_t ws_size,
                              hipStream_t stream)
{
    (void)in_sizes; (void)n_in; (void)out_size; (void)ws_size;

    const float* x      = (const float*)d_in[0];
    const float* l1_iw  = (const float*)d_in[1];
    const float* l1_ib  = (const float*)d_in[2];
    const float* l1_sw  = (const float*)d_in[3];
    const float* l1_ss  = (const float*)d_in[4];
    const float* l1_smu = (const float*)d_in[5];
    const float* l1_se  = (const float*)d_in[6];
    const float* l1_w   = (const float*)d_in[8];
    const float* l1_sg  = (const float*)d_in[9];
    const float* l1_mu  = (const float*)d_in[10];
    const float* l1_er  = (const float*)d_in[11];
    const float* l1_gl  = (const float*)d_in[13];
    const float* l1_vl  = (const float*)d_in[14];
    const float* l1_cm  = (const float*)d_in[15];
    const float* l1_ow  = (const float*)d_in[16];
    const float* l1_ob  = (const float*)d_in[17];
    const float* l2_iw  = (const float*)d_in[18];
    const float* l2_ib  = (const float*)d_in[19];
    const float* l2_sw  = (const float*)d_in[20];
    const float* l2_ss  = (const float*)d_in[21];
    const float* l2_smu = (const float*)d_in[22];
    const float* l2_se  = (const float*)d_in[23];
    const float* l2_w   = (const float*)d_in[25];
    const float* l2_sg  = (const float*)d_in[26];
    const float* l2_mu  = (const float*)d_in[27];
    const float* l2_er  = (const float*)d_in[28];
    const float* l2_gl  = (const float*)d_in[30];
    const float* l2_vl  = (const float*)d_in[31];
    const float* l2_cm  = (const float*)d_in[32];
    const float* l2_ow  = (const float*)d_in[33];
    const float* l2_ob  = (const float*)d_in[34];
    const float* fcw    = (const float*)d_in[35];
    const float* fcb    = (const float*)d_in[36];

    char*  base = (char*)d_ws;
    size_t off  = 0;
    auto alloc = [&](size_t bytes) -> char* {
        char* p = base + off;
        off += (bytes + 255) & ~(size_t)255;
        return p;
    };

    float*   h1   = (float*)  alloc((size_t)B_SZ * T_STEPS * U1 * 4);
    float*   h2   = (float*)  alloc((size_t)B_SZ * T_STEPS * 64 * 4);
    __half2* AB1s = (__half2*)alloc((size_t)S1 * U1 * 4);
    __half*  W1s  = (__half*) alloc((size_t)S1 * U1 * 2);
    __half2* AB1r = (__half2*)alloc((size_t)U1 * U1 * 4);
    __half*  W1r  = (__half*) alloc((size_t)U1 * U1 * 2);
    __half2* AB2s = (__half2*)alloc((size_t)S2 * U2 * 4);
    __half*  W2s  = (__half*) alloc((size_t)S2 * U2 * 2);
    __half2* AB2r = (__half2*)alloc((size_t)U2 * U2 * 4);
    __half*  W2r  = (__half*) alloc((size_t)U2 * U2 * 2);
    float*   cmt1 = (float*)  alloc(U1 * 4);
    float*   nb1  = (float*)  alloc(U1 * 4);
    float*   db1  = (float*)  alloc(U1 * 4);
    float*   cmt2 = (float*)  alloc(U2 * 4);
    float*   nb2  = (float*)  alloc(U2 * 4);
    float*   db2  = (float*)  alloc(U2 * 4);
    unsigned int* flags = (unsigned int*)alloc((size_t)B_SZ * T_STEPS * 4);

    // reset pipeline flags every call (graph-capturable async memset)
    hipMemsetAsync(flags, 0, (size_t)B_SZ * T_STEPS * 4, stream);

    prep_half<<<(S1 * U1 + 255) / 256, 256, 0, stream>>>(l1_ss, l1_smu, l1_sw, l1_se, AB1s, W1s, S1 * U1);
    prep_half<<<(U1 * U1 + 255) / 256, 256, 0, stream>>>(l1_sg, l1_mu,  l1_w,  l1_er, AB1r, W1r, U1 * U1);
    prep_half<<<(S2 * U2 + 255) / 256, 256, 0, stream>>>(l2_ss, l2_smu, l2_sw, l2_se, AB2s, W2s, S2 * U2);
    prep_half<<<(U2 * U2 + 255) / 256, 256, 0, stream>>>(l2_sg, l2_mu,  l2_w,  l2_er, AB2r, W2r, U2 * U2);
    prep_vec<<<1, 256, 0, stream>>>(l1_gl, l1_vl, l1_cm, cmt1, nb1, db1, U1);
    prep_vec<<<1, 256, 0, stream>>>(l2_gl, l2_vl, l2_cm, cmt2, nb2, db2, U2);

    ltc_pipe<<<128, 512, 0, stream>>>(
        x, l1_iw, l1_ib, AB1s, W1s, AB1r, W1r, cmt1, nb1, db1, l1_ow, l1_ob,
        l2_iw, l2_ib, AB2s, W2s, AB2r, W2r, cmt2, nb2, db2, l2_ow, l2_ob,
        h1, h2, flags);

    fc_head<<<B_SZ * T_STEPS / 8, 512, 0, stream>>>(h2, fcw, fcb, (float*)d_out);
}

// Round 4
// 27967.432 us; speedup vs baseline: 5.1569x; 5.1569x over previous
//
#include <hip/hip_runtime.h>
#include <hip/hip_fp16.h>

#define B_SZ    64
#define T_STEPS 512
#define U1      128
#define S1      128
#define U2      256
#define S2      128
#define NUNF    6

__device__ __forceinline__ float fast_exp2(float x) { return __builtin_amdgcn_exp2f(x); }
__device__ __forceinline__ float fast_rcp(float x)  { return __builtin_amdgcn_rcpf(x); }

// ---------------------------------------------------------------------------
// Param transform, fp16-packed SoA: AB = half2(sigma*log2e, mu*sigma*log2e),
// W = half(w*erev).  sigmoid((v-mu)*sigma) = 1/(1+exp2(B - A*v)); |W| = w*mask.
// 6 bytes per (s,uo) pair streamed in the hot loop.
// ---------------------------------------------------------------------------
__global__ void prep_half(const float* __restrict__ sg, const float* __restrict__ mu,
                          const float* __restrict__ w, const float* __restrict__ er,
                          __half2* __restrict__ AB, __half* __restrict__ W, int n)
{
    int i = blockIdx.x * 256 + threadIdx.x;
    if (i >= n) return;
    const float L2E = 1.4426950408889634f;
    float a = sg[i] * L2E;
    AB[i] = __floats2half2_rn(a, mu[i] * a);
    W[i]  = __float2half_rn(w[i] * er[i]);
}

__global__ void prep_vec(const float* __restrict__ gleak, const float* __restrict__ vleak,
                         const float* __restrict__ cm,
                         float* __restrict__ cmt, float* __restrict__ nb,
                         float* __restrict__ db, int n)
{
    int i = blockIdx.x * 256 + threadIdx.x;
    if (i >= n) return;
    float c6 = cm[i] * 6.f;
    float gl = gleak[i];
    cmt[i] = c6;
    nb[i]  = gl * vleak[i];
    db[i]  = c6 + gl + 1e-8f;
}

__device__ __forceinline__ void pair_eval(__half2 ab, __half w, float vj,
                                          float& an, float& ad)
{
    float a  = __low2float(ab);
    float bb = __high2float(ab);
    float ww = __half2float(w);
    float e  = fast_exp2(bb - a * vj);
    float r  = fast_rcp(1.f + e);
    an = fmaf(ww, r, an);
    ad = fmaf(fabsf(ww), r, ad);
}

// ---------------------------------------------------------------------------
// Layer 1: S=128, U=128. 1024 threads: uo=tid&127, g=tid>>7 (8 groups x 16 s).
// ---------------------------------------------------------------------------
__global__ __launch_bounds__(1024, 1) void ltc1(
    const float* __restrict__ x,
    const float* __restrict__ in_w, const float* __restrict__ in_b,
    const __half2* __restrict__ ABs, const __half* __restrict__ Ws,
    const __half2* __restrict__ ABr, const __half* __restrict__ Wr,
    const float* __restrict__ cmt, const float* __restrict__ nbv, const float* __restrict__ dbv,
    const float* __restrict__ ow, const float* __restrict__ ob,
    float* __restrict__ h1)
{
    const int b   = blockIdx.x;
    const int tid = threadIdx.x;
    const int uo  = tid & (U1 - 1);
    const int g   = tid >> 7;              // 0..7, each covers 16 inputs

    __shared__ float  v1[U1];
    __shared__ float  ibuf[S1];
    __shared__ float2 red[8][U1];
    __shared__ float  nbs[U1], dbs[U1];

    float c_cmt = 0, c_nb = 0, c_db = 0, c_iw = 0, c_ib = 0, c_ow = 0, c_ob = 0;
    if (tid < U1) {
        v1[tid] = 0.f;
        c_cmt = cmt[tid]; c_nb = nbv[tid]; c_db = dbv[tid];
        c_iw = in_w[tid]; c_ib = in_b[tid];
        c_ow = ow[tid];   c_ob = ob[tid];
    }
    const float* xb = x  + (size_t)b * T_STEPS * S1;
    float*       hb = h1 + (size_t)b * T_STEPS * U1;

    const __half2* pABs = ABs + (size_t)(g * 16) * U1 + uo;
    const __half*  pWs  = Ws  + (size_t)(g * 16) * U1 + uo;
    const __half2* pABr = ABr + (size_t)(g * 16) * U1 + uo;
    const __half*  pWr  = Wr  + (size_t)(g * 16) * U1 + uo;

    for (int t = 0; t < T_STEPS; ++t) {
        if (tid < S1) ibuf[tid] = fmaf(xb[t * S1 + tid], c_iw, c_ib);
        __syncthreads();

        {   // sensory partials: 16 pairs/thread
            float an = 0.f, ad = 0.f;
            #pragma unroll 4
            for (int jj = 0; jj < 4; ++jj) {
                float4 iv = *reinterpret_cast<const float4*>(&ibuf[g * 16 + jj * 4]);
                float vals[4] = {iv.x, iv.y, iv.z, iv.w};
                #pragma unroll
                for (int q = 0; q < 4; ++q) {
                    int j = jj * 4 + q;
                    pair_eval(pABs[(size_t)j * U1], pWs[(size_t)j * U1], vals[q], an, ad);
                }
            }
            red[g][uo] = make_float2(an, ad);
        }
        __syncthreads();
        if (tid < U1) {
            float sn = c_nb, sd = c_db;
            #pragma unroll
            for (int gg = 0; gg < 8; ++gg) { float2 r = red[gg][tid]; sn += r.x; sd += r.y; }
            nbs[tid] = sn; dbs[tid] = sd;
        }
        __syncthreads();

        for (int k = 0; k < NUNF; ++k) {
            float an = 0.f, ad = 0.f;
            #pragma unroll 4
            for (int jj = 0; jj < 4; ++jj) {
                float4 vv = *reinterpret_cast<const float4*>(&v1[g * 16 + jj * 4]);
                float vals[4] = {vv.x, vv.y, vv.z, vv.w};
                #pragma unroll
                for (int q = 0; q < 4; ++q) {
                    int j = jj * 4 + q;
                    pair_eval(pABr[(size_t)j * U1], pWr[(size_t)j * U1], vals[q], an, ad);
                }
            }
            red[g][uo] = make_float2(an, ad);
            __syncthreads();
            if (tid < U1) {
                float sn = nbs[tid], sd = dbs[tid];
                #pragma unroll
                for (int gg = 0; gg < 8; ++gg) { float2 r = red[gg][tid]; sn += r.x; sd += r.y; }
                v1[tid] = fmaf(c_cmt, v1[tid], sn) * fast_rcp(sd);
            }
            __syncthreads();
        }
        if (tid < U1) hb[t * U1 + tid] = fmaf(v1[tid], c_ow, c_ob);
    }
}

// ---------------------------------------------------------------------------
// Layer 2: S=128, U=256. 1024 threads: uo=tid&255, g=tid>>8 (4 groups).
// Sensory: 32 pairs/thread; recurrent: 64 pairs/thread.
// ---------------------------------------------------------------------------
__global__ __launch_bounds__(1024, 1) void ltc2(
    const float* __restrict__ h1,
    const float* __restrict__ in_w, const float* __restrict__ in_b,
    const __half2* __restrict__ ABs, const __half* __restrict__ Ws,
    const __half2* __restrict__ ABr, const __half* __restrict__ Wr,
    const float* __restrict__ cmt, const float* __restrict__ nbv, const float* __restrict__ dbv,
    const float* __restrict__ ow, const float* __restrict__ ob,
    float* __restrict__ h2)                      // [64][512][64]
{
    const int b   = blockIdx.x;
    const int tid = threadIdx.x;
    const int uo  = tid & (U2 - 1);
    const int g   = tid >> 8;              // 0..3

    __shared__ float  v2[U2];
    __shared__ float  ibuf[S2];
    __shared__ float2 red[4][U2];
    __shared__ float  nbs[U2], dbs[U2];

    float c_cmt = 0, c_nb = 0, c_db = 0;
    if (tid < U2) {
        v2[tid] = 0.f;
        c_cmt = cmt[tid]; c_nb = nbv[tid]; c_db = dbv[tid];
    }
    float c_iw = 0, c_ib = 0;
    if (tid < S2) { c_iw = in_w[tid]; c_ib = in_b[tid]; }
    float c_ow = 0, c_ob = 0;
    if (tid < 64) { c_ow = ow[tid]; c_ob = ob[tid]; }

    const float* hb = h1 + (size_t)b * T_STEPS * S2;
    float*       op = h2 + (size_t)b * T_STEPS * 64;

    const __half2* pABs = ABs + (size_t)(g * 32) * U2 + uo;
    const __half*  pWs  = Ws  + (size_t)(g * 32) * U2 + uo;
    const __half2* pABr = ABr + (size_t)(g * 64) * U2 + uo;
    const __half*  pWr  = Wr  + (size_t)(g * 64) * U2 + uo;

    for (int t = 0; t < T_STEPS; ++t) {
        if (tid < S2) ibuf[tid] = fmaf(hb[t * S2 + tid], c_iw, c_ib);
        __syncthreads();

        {   // sensory partials: 32 pairs/thread
            float an = 0.f, ad = 0.f;
            #pragma unroll 4
            for (int jj = 0; jj < 8; ++jj) {
                float4 iv = *reinterpret_cast<const float4*>(&ibuf[g * 32 + jj * 4]);
                float vals[4] = {iv.x, iv.y, iv.z, iv.w};
                #pragma unroll
                for (int q = 0; q < 4; ++q) {
                    int j = jj * 4 + q;
                    pair_eval(pABs[(size_t)j * U2], pWs[(size_t)j * U2], vals[q], an, ad);
                }
            }
            red[g][uo] = make_float2(an, ad);
        }
        __syncthreads();
        if (tid < U2) {
            float2 r0 = red[0][tid], r1 = red[1][tid], r2 = red[2][tid], r3 = red[3][tid];
            nbs[tid] = c_nb + ((r0.x + r1.x) + (r2.x + r3.x));
            dbs[tid] = c_db + ((r0.y + r1.y) + (r2.y + r3.y));
        }
        __syncthreads();

        for (int k = 0; k < NUNF; ++k) {
            float an = 0.f, ad = 0.f;   // recurrent: 64 pairs/thread
            #pragma unroll 4
            for (int jj = 0; jj < 16; ++jj) {
                float4 vv = *reinterpret_cast<const float4*>(&v2[g * 64 + jj * 4]);
                float vals[4] = {vv.x, vv.y, vv.z, vv.w};
                #pragma unroll
                for (int q = 0; q < 4; ++q) {
                    int j = jj * 4 + q;
                    pair_eval(pABr[(size_t)j * U2], pWr[(size_t)j * U2], vals[q], an, ad);
                }
            }
            red[g][uo] = make_float2(an, ad);
            __syncthreads();
            if (tid < U2) {
                float2 r0 = red[0][tid], r1 = red[1][tid], r2 = red[2][tid], r3 = red[3][tid];
                float wn = nbs[tid] + ((r0.x + r1.x) + (r2.x + r3.x));
                float wd = dbs[tid] + ((r0.y + r1.y) + (r2.y + r3.y));
                v2[tid] = fmaf(c_cmt, v2[tid], wn) * fast_rcp(wd);
            }
            __syncthreads();
        }
        if (tid < 64) op[t * 64 + tid] = fmaf(v2[tid], c_ow, c_ob);
        __syncthreads();
    }
}

// ---------------------------------------------------------------------------
// FC head: out[b,t,o] = fcb[o] + sum_k h2[b,t,k] * fcw[o,k]
// ---------------------------------------------------------------------------
__global__ __launch_bounds__(512, 1) void fc_head(
    const float* __restrict__ h2, const float* __restrict__ fcw,
    const float* __restrict__ fcb, float* __restrict__ out)
{
    __shared__ float fwT[64 * 64];
    __shared__ float hs[8 * 64];
    const int tid = threadIdx.x;
    for (int i = tid; i < 64 * 64; i += 512) {
        int o = i >> 6, k = i & 63;
        fwT[k * 64 + o] = fcw[i];
    }
    size_t base = (size_t)blockIdx.x * 8 * 64;
    hs[tid] = h2[base + tid];
    __syncthreads();
    const int o = tid & 63, tt = tid >> 6;
    float acc = fcb[o];
    #pragma unroll
    for (int k = 0; k < 64; ++k)
        acc = fmaf(hs[tt * 64 + k], fwT[k * 64 + o], acc);
    out[base + tt * 64 + o] = acc;
}

// ---------------------------------------------------------------------------
extern "C" void kernel_launch(void* const* d_in, const int* in_sizes, int n_in,
                              void* d_out, int out_size, void* d_ws, size_t ws_size,
                              hipStream_t stream)
{
    (void)in_sizes; (void)n_in; (void)out_size; (void)ws_size;

    const float* x      = (const float*)d_in[0];
    const float* l1_iw  = (const float*)d_in[1];
    const float* l1_ib  = (const float*)d_in[2];
    const float* l1_sw  = (const float*)d_in[3];
    const float* l1_ss  = (const float*)d_in[4];
    const float* l1_smu = (const float*)d_in[5];
    const float* l1_se  = (const float*)d_in[6];
    const float* l1_w   = (const float*)d_in[8];
    const float* l1_sg  = (const float*)d_in[9];
    const float* l1_mu  = (const float*)d_in[10];
    const float* l1_er  = (const float*)d_in[11];
    const float* l1_gl  = (const float*)d_in[13];
    const float* l1_vl  = (const float*)d_in[14];
    const float* l1_cm  = (const float*)d_in[15];
    const float* l1_ow  = (const float*)d_in[16];
    const float* l1_ob  = (const float*)d_in[17];
    const float* l2_iw  = (const float*)d_in[18];
    const float* l2_ib  = (const float*)d_in[19];
    const float* l2_sw  = (const float*)d_in[20];
    const float* l2_ss  = (const float*)d_in[21];
    const float* l2_smu = (const float*)d_in[22];
    const float* l2_se  = (const float*)d_in[23];
    const float* l2_w   = (const float*)d_in[25];
    const float* l2_sg  = (const float*)d_in[26];
    const float* l2_mu  = (const float*)d_in[27];
    const float* l2_er  = (const float*)d_in[28];
    const float* l2_gl  = (const float*)d_in[30];
    const float* l2_vl  = (const float*)d_in[31];
    const float* l2_cm  = (const float*)d_in[32];
    const float* l2_ow  = (const float*)d_in[33];
    const float* l2_ob  = (const float*)d_in[34];
    const float* fcw    = (const float*)d_in[35];
    const float* fcb    = (const float*)d_in[36];

    char*  base = (char*)d_ws;
    size_t off  = 0;
    auto alloc = [&](size_t bytes) -> char* {
        char* p = base + off;
        off += (bytes + 255) & ~(size_t)255;
        return p;
    };

    float*   h1   = (float*)  alloc((size_t)B_SZ * T_STEPS * U1 * 4);
    float*   h2   = (float*)  alloc((size_t)B_SZ * T_STEPS * 64 * 4);
    __half2* AB1s = (__half2*)alloc((size_t)S1 * U1 * 4);
    __half*  W1s  = (__half*) alloc((size_t)S1 * U1 * 2);
    __half2* AB1r = (__half2*)alloc((size_t)U1 * U1 * 4);
    __half*  W1r  = (__half*) alloc((size_t)U1 * U1 * 2);
    __half2* AB2s = (__half2*)alloc((size_t)S2 * U2 * 4);
    __half*  W2s  = (__half*) alloc((size_t)S2 * U2 * 2);
    __half2* AB2r = (__half2*)alloc((size_t)U2 * U2 * 4);
    __half*  W2r  = (__half*) alloc((size_t)U2 * U2 * 2);
    float*   cmt1 = (float*)  alloc(U1 * 4);
    float*   nb1  = (float*)  alloc(U1 * 4);
    float*   db1  = (float*)  alloc(U1 * 4);
    float*   cmt2 = (float*)  alloc(U2 * 4);
    float*   nb2  = (float*)  alloc(U2 * 4);
    float*   db2  = (float*)  alloc(U2 * 4);

    prep_half<<<(S1 * U1 + 255) / 256, 256, 0, stream>>>(l1_ss, l1_smu, l1_sw, l1_se, AB1s, W1s, S1 * U1);
    prep_half<<<(U1 * U1 + 255) / 256, 256, 0, stream>>>(l1_sg, l1_mu,  l1_w,  l1_er, AB1r, W1r, U1 * U1);
    prep_half<<<(S2 * U2 + 255) / 256, 256, 0, stream>>>(l2_ss, l2_smu, l2_sw, l2_se, AB2s, W2s, S2 * U2);
    prep_half<<<(U2 * U2 + 255) / 256, 256, 0, stream>>>(l2_sg, l2_mu,  l2_w,  l2_er, AB2r, W2r, U2 * U2);
    prep_vec<<<1, 256, 0, stream>>>(l1_gl, l1_vl, l1_cm, cmt1, nb1, db1, U1);
    prep_vec<<<1, 256, 0, stream>>>(l2_gl, l2_vl, l2_cm, cmt2, nb2, db2, U2);

    ltc1<<<B_SZ, 1024, 0, stream>>>(x, l1_iw, l1_ib, AB1s, W1s, AB1r, W1r,
                                    cmt1, nb1, db1, l1_ow, l1_ob, h1);
    ltc2<<<B_SZ, 1024, 0, stream>>>(h1, l2_iw, l2_ib, AB2s, W2s, AB2r, W2r,
                                    cmt2, nb2, db2, l2_ow, l2_ob, h2);
    fc_head<<<B_SZ * T_STEPS / 8, 512, 0, stream>>>(h2, fcw, fcb, (float*)d_out);
}